// Round 21
// baseline (51.226 us; speedup 1.0000x reference)
//
#include <hip/hip_runtime.h>

typedef __attribute__((ext_vector_type(2))) float f32x2;

#define W 4096
#define H 4096
#define NT 256
#define COLS 512                 // columns per block (2 per thread)
#define SR 64                    // output rows per block strip (was 32)
#define GROUP 4                  // rows staged per barrier (1 per wave, DMA)
#define NSTAGE (SR + 14)         // 78 staged rows contribute
#define NG 20                    // 20 groups of 4 (80 slots, last 2 guarded)
#define LW 528                   // staged row: float f <-> col c0-8+f (exact)
#define RAD 7
#define PEND 18                  // 15 + GROUP - 1  (fits the 64-VGPR budget)

__device__ __forceinline__ void gl_lds16(float* lds, const float* g) {
    __builtin_amdgcn_global_load_lds(
        (const __attribute__((address_space(1))) void*)g,
        (__attribute__((address_space(3))) void*)lds, 16, 0, 0);
}
__device__ __forceinline__ void gl_lds4(float* lds, const float* g) {
    __builtin_amdgcn_global_load_lds(
        (const __attribute__((address_space(1))) void*)g,
        (__attribute__((address_space(3))) void*)lds, 4, 0, 0);
}

__global__ __launch_bounds__(NT, 4) void multibox_kernel(
    const float* __restrict__ x, const float* __restrict__ base,
    float* __restrict__ out)
{
    __shared__ float buf[2][GROUP][LW];   // 16,896 B

    const int t  = threadIdx.x;
    const int w  = t >> 6;                // wave id: stages row w of each group
    const int l  = t & 63;                // lane
    const int c0 = blockIdx.x * COLS;
    const int i0 = blockIdx.y * SR;

    // Boustrophedon (r20 win): odd strips sweep bottom-up so vertical
    // neighbors touch their shared 14 halo rows close in time -> L2 hits.
    const bool flip = blockIdx.y & 1;

    const float w3  = 1.f/(7.f*9.f);
    const float w5  = 1.f/(7.f*25.f);
    const float w7  = 1.f/(7.f*49.f);
    const float w9  = 1.f/(7.f*81.f);
    const float w11 = 1.f/(7.f*121.f);
    const float w13 = 1.f/(7.f*169.f);
    const float w15 = 1.f/(7.f*225.f);

    // Exact-edge 4-op DMA per row (float f <-> col c0-8+f, f = 0..527):
    //  L : f 0..63    4B/lane x64, per-lane clamp -> exact edge replicate
    //  M1: f 64..319  16B/lane x64, cols c0+56..c0+315 always in-range
    //  M2: f 320..511 16B/lane, lanes 0..47, cols <= c0+503 in-range
    //  R : f 512..527 4B/lane, lanes 0..15, per-lane clamp -> exact replicate
    // Reads exactly 528 floats/row (r9 3-op layout read 576, +9%); no
    // block-0 patch step -> all blocks uniform, no extra barriers.
    const int colL  = min(max(c0 -   8 +     l, 0), W - 1);
    const int colM1 =         c0 +  56 + 4 * l;
    const int colM2 =         c0 + 312 + 4 * l;
    const int colR  = min(    c0 + 504 +     l,     W - 1);

    // each wave DMAs its one row (logical idx -> physical srow) of group g
    auto stage = [&](int g, int b) {
        const int idx  = g * GROUP + w;                       // logical step
        const int srow = flip ? (NSTAGE - 1 - idx) : idx;     // physical offset
        const int rc   = min(max(i0 - RAD + srow, 0), H - 1);
        const float* rp = x + (size_t)rc * W;
        float* lb = &buf[b][w][0];
        gl_lds4(lb, rp + colL);
        gl_lds16(lb + 64, rp + colM1);
        if (l < 48) gl_lds16(lb + 320, rp + colM2);
        if (l < 16) gl_lds4 (lb + 512, rp + colR);
    };

    // Pnd[p] accumulates LOGICAL output row (4g - 14 + p) before group g.
    // rr / p compile-time (inner unrolls); g stays RUNTIME (rounds 4/7 lesson).
    f32x2 Pnd[PEND];
#pragma unroll
    for (int q = 0; q < PEND; ++q) Pnd[q] = f32x2{0.f, 0.f};

    auto compute_group = [&](int b, int g) {
#pragma unroll
        for (int rr = 0; rr < GROUP; ++rr) {
            if (g * GROUP + rr < NSTAGE) {
                const float* p = &buf[b][rr][2 * t];   // floats 2t .. 2t+17
                f32x2 q2[9];
#pragma unroll
                for (int i = 0; i < 9; ++i) q2[i] = *(const f32x2*)(p + 2 * i);

                auto PR = [&](int a) -> f32x2 {        // cols {j-8+a, j-7+a}
                    if ((a & 1) == 0) return q2[a / 2];
                    f32x2 r;
                    r.x = q2[a / 2].y;
                    r.y = q2[a / 2 + 1].x;
                    return r;
                };

                f32x2 s3  = PR(7) + PR(8) + PR(9);
                f32x2 s5  = s3  + PR(6) + PR(10);
                f32x2 s7  = s5  + PR(5) + PR(11);
                f32x2 s9  = s7  + PR(4) + PR(12);
                f32x2 s11 = s9  + PR(3) + PR(13);
                f32x2 s13 = s11 + PR(2) + PR(14);
                f32x2 s15 = s13 + PR(1) + PR(15);

                f32x2 c7 = f32x2{w15, w15} * s15;
                f32x2 c6 = c7 + f32x2{w13, w13} * s13;
                f32x2 c5 = c6 + f32x2{w11, w11} * s11;
                f32x2 c4 = c5 + f32x2{w9 , w9 } * s9;
                f32x2 c3 = c4 + f32x2{w7 , w7 } * s7;
                f32x2 c2 = c3 + f32x2{w5 , w5 } * s5;
                f32x2 c1 = c2 + f32x2{w3 , w3 } * s3;

                Pnd[rr +  0] += c7; Pnd[rr +  1] += c6; Pnd[rr +  2] += c5;
                Pnd[rr +  3] += c4; Pnd[rr +  4] += c3; Pnd[rr +  5] += c2;
                Pnd[rr +  6] += c1; Pnd[rr +  7] += c1; Pnd[rr +  8] += c1;
                Pnd[rr +  9] += c2; Pnd[rr + 10] += c3; Pnd[rr + 11] += c4;
                Pnd[rr + 12] += c5; Pnd[rr + 13] += c6; Pnd[rr + 14] += c7;
            }
        }

        // emit completed logical rows ol = 4g - 14 + p -> physical row
#pragma unroll
        for (int p = 0; p < GROUP; ++p) {
            const int ol = 4 * g - 14 + p;
            if (ol >= 0 && ol < SR) {
                const int orow = flip ? (i0 + SR - 1 - ol) : (i0 + ol);
                const size_t bi = (size_t)orow * W + c0 + 2 * t;
                f32x2 bm = *(const f32x2*)(base + bi);
                f32x2 ov = Pnd[p] * bm;
                __builtin_nontemporal_store(ov, (f32x2*)(out + bi));
            }
        }

        // shift window by GROUP (static indices)
#pragma unroll
        for (int p = 0; p < PEND - GROUP; ++p) Pnd[p] = Pnd[p + GROUP];
#pragma unroll
        for (int p = PEND - GROUP; p < PEND; ++p) Pnd[p] = f32x2{0.f, 0.f};
    };

    stage(0, 0);
    __syncthreads();                       // drains DMA (vmcnt) + orders LDS

    // MUST stay rolled (round-7 lesson: unroll hoists loads -> spill)
#pragma clang loop unroll(disable)
    for (int g = 0; g < NG - 1; ++g) {
        stage(g + 1, (g + 1) & 1);   // 4 DMA instrs/wave, issued before compute
        compute_group(g & 1, g);     // ds_read + VALU + emit (hides DMA latency)
        __syncthreads();             // next group's rows landed
    }
    compute_group((NG - 1) & 1, NG - 1);
}

extern "C" void kernel_launch(void* const* d_in, const int* in_sizes, int n_in,
                              void* d_out, int out_size, void* d_ws, size_t ws_size,
                              hipStream_t stream) {
    const float* x    = (const float*)d_in[0];
    const float* base = (const float*)d_in[1];
    float* out        = (float*)d_out;

    dim3 grid(W / COLS, H / SR);   // (8, 64) = 512 blocks
    multibox_kernel<<<grid, dim3(NT), 0, stream>>>(x, base, out);
}

// Round 22
// 42.695 us; speedup vs baseline: 1.1998x; 1.1998x over previous
//
#include <hip/hip_runtime.h>

typedef __attribute__((ext_vector_type(2))) float f32x2;

#define W 4096
#define H 4096
#define NT 256
#define COLS 512                 // columns per block (2 per thread)
#define SR 32                    // output rows per block strip
#define GROUP 4                  // rows staged per barrier (1 per wave, DMA)
#define NSTAGE (SR + 14)         // 46 staged rows contribute
#define NG 12                    // 12 groups of 4
#define LW 528                   // staged row: float f <-> col c0-8+f (exact)
#define RAD 7
#define PEND 18                  // 15 + GROUP - 1  (fits the 64-VGPR budget)

__device__ __forceinline__ void gl_lds16(float* lds, const float* g) {
    __builtin_amdgcn_global_load_lds(
        (const __attribute__((address_space(1))) void*)g,
        (__attribute__((address_space(3))) void*)lds, 16, 0, 0);
}
__device__ __forceinline__ void gl_lds4(float* lds, const float* g) {
    __builtin_amdgcn_global_load_lds(
        (const __attribute__((address_space(1))) void*)g,
        (__attribute__((address_space(3))) void*)lds, 4, 0, 0);
}

__global__ __launch_bounds__(NT, 4) void multibox_kernel(
    const float* __restrict__ x, const float* __restrict__ base,
    float* __restrict__ out)
{
    __shared__ float buf[2][GROUP][LW];   // 16,896 B

    const int t  = threadIdx.x;
    const int w  = t >> 6;                // wave id: stages row w of each group
    const int l  = t & 63;                // lane
    const int c0 = blockIdx.x * COLS;
    const int i0 = blockIdx.y * SR;

    // Boustrophedon (r20 win, -13MB FETCH): odd strips sweep bottom-up so
    // vertical neighbors touch their shared 14 halo rows close in time.
    const bool flip = blockIdx.y & 1;

    const float w3  = 1.f/(7.f*9.f);
    const float w5  = 1.f/(7.f*25.f);
    const float w7  = 1.f/(7.f*49.f);
    const float w9  = 1.f/(7.f*81.f);
    const float w11 = 1.f/(7.f*121.f);
    const float w13 = 1.f/(7.f*169.f);
    const float w15 = 1.f/(7.f*225.f);

    // Exact-edge 4-op DMA per row (float f <-> col c0-8+f, f = 0..527):
    //  L : f 0..63    4B/lane x64, per-lane clamp -> exact edge replicate
    //  M1: f 64..319  16B/lane x64, always in-range
    //  M2: f 320..511 16B/lane, lanes 0..47, in-range
    //  R : f 512..527 4B/lane, lanes 0..15, per-lane clamp -> exact replicate
    // Reads exactly the 528 floats needed (r20's 576-float layout pulled 64
    // extra floats/row from the x-NEIGHBOR panel -> cross-XCD L2 miss -> ~8MB
    // extra HBM fetch). Also: no block-0 patch step / extra barriers.
    const int colL  = min(max(c0 -   8 +     l, 0), W - 1);
    const int colM1 =         c0 +  56 + 4 * l;
    const int colM2 =         c0 + 312 + 4 * l;
    const int colR  = min(    c0 + 504 +     l,     W - 1);

    // each wave DMAs its one row (logical idx -> physical srow) of group g
    auto stage = [&](int g, int b) {
        const int idx  = g * GROUP + w;                       // logical step
        const int srow = flip ? (NSTAGE - 1 - idx) : idx;     // physical offset
        const int rc   = min(max(i0 - RAD + srow, 0), H - 1);
        const float* rp = x + (size_t)rc * W;
        float* lb = &buf[b][w][0];
        gl_lds4(lb, rp + colL);
        gl_lds16(lb + 64, rp + colM1);
        if (l < 48) gl_lds16(lb + 320, rp + colM2);
        if (l < 16) gl_lds4 (lb + 512, rp + colR);
    };

    // Pnd[p] accumulates LOGICAL output row (4g - 14 + p) before group g.
    // rr / p compile-time (inner unrolls); g stays RUNTIME (rounds 4/7 lesson).
    f32x2 Pnd[PEND];
#pragma unroll
    for (int q = 0; q < PEND; ++q) Pnd[q] = f32x2{0.f, 0.f};

    auto compute_group = [&](int b, int g) {
#pragma unroll
        for (int rr = 0; rr < GROUP; ++rr) {
            if (g * GROUP + rr < NSTAGE) {
                const float* p = &buf[b][rr][2 * t];   // floats 2t .. 2t+17
                f32x2 q2[9];
#pragma unroll
                for (int i = 0; i < 9; ++i) q2[i] = *(const f32x2*)(p + 2 * i);

                auto PR = [&](int a) -> f32x2 {        // cols {j-8+a, j-7+a}
                    if ((a & 1) == 0) return q2[a / 2];
                    f32x2 r;
                    r.x = q2[a / 2].y;
                    r.y = q2[a / 2 + 1].x;
                    return r;
                };

                f32x2 s3  = PR(7) + PR(8) + PR(9);
                f32x2 s5  = s3  + PR(6) + PR(10);
                f32x2 s7  = s5  + PR(5) + PR(11);
                f32x2 s9  = s7  + PR(4) + PR(12);
                f32x2 s11 = s9  + PR(3) + PR(13);
                f32x2 s13 = s11 + PR(2) + PR(14);
                f32x2 s15 = s13 + PR(1) + PR(15);

                f32x2 c7 = f32x2{w15, w15} * s15;
                f32x2 c6 = c7 + f32x2{w13, w13} * s13;
                f32x2 c5 = c6 + f32x2{w11, w11} * s11;
                f32x2 c4 = c5 + f32x2{w9 , w9 } * s9;
                f32x2 c3 = c4 + f32x2{w7 , w7 } * s7;
                f32x2 c2 = c3 + f32x2{w5 , w5 } * s5;
                f32x2 c1 = c2 + f32x2{w3 , w3 } * s3;

                Pnd[rr +  0] += c7; Pnd[rr +  1] += c6; Pnd[rr +  2] += c5;
                Pnd[rr +  3] += c4; Pnd[rr +  4] += c3; Pnd[rr +  5] += c2;
                Pnd[rr +  6] += c1; Pnd[rr +  7] += c1; Pnd[rr +  8] += c1;
                Pnd[rr +  9] += c2; Pnd[rr + 10] += c3; Pnd[rr + 11] += c4;
                Pnd[rr + 12] += c5; Pnd[rr + 13] += c6; Pnd[rr + 14] += c7;
            }
        }

        // emit completed logical rows ol = 4g - 14 + p -> physical row
#pragma unroll
        for (int p = 0; p < GROUP; ++p) {
            const int ol = 4 * g - 14 + p;
            if (ol >= 0 && ol < SR) {
                const int orow = flip ? (i0 + SR - 1 - ol) : (i0 + ol);
                const size_t bi = (size_t)orow * W + c0 + 2 * t;
                f32x2 bm = *(const f32x2*)(base + bi);
                f32x2 ov = Pnd[p] * bm;
                __builtin_nontemporal_store(ov, (f32x2*)(out + bi));
            }
        }

        // shift window by GROUP (static indices)
#pragma unroll
        for (int p = 0; p < PEND - GROUP; ++p) Pnd[p] = Pnd[p + GROUP];
#pragma unroll
        for (int p = PEND - GROUP; p < PEND; ++p) Pnd[p] = f32x2{0.f, 0.f};
    };

    stage(0, 0);
    __syncthreads();                       // drains DMA (vmcnt) + orders LDS

    // MUST stay rolled (round-7 lesson: unroll hoists loads -> spill)
#pragma clang loop unroll(disable)
    for (int g = 0; g < NG - 1; ++g) {
        stage(g + 1, (g + 1) & 1);   // 4 DMA instrs/wave, issued before compute
        compute_group(g & 1, g);     // ds_read + VALU + emit (hides DMA latency)
        __syncthreads();             // next group's rows landed
    }
    compute_group((NG - 1) & 1, NG - 1);
}

extern "C" void kernel_launch(void* const* d_in, const int* in_sizes, int n_in,
                              void* d_out, int out_size, void* d_ws, size_t ws_size,
                              hipStream_t stream) {
    const float* x    = (const float*)d_in[0];
    const float* base = (const float*)d_in[1];
    float* out        = (float*)d_out;

    dim3 grid(W / COLS, H / SR);   // (8, 128) = 1024 blocks
    multibox_kernel<<<grid, dim3(NT), 0, stream>>>(x, base, out);
}